// Round 10
// baseline (91.783 us; speedup 1.0000x reference)
//
#include <hip/hip_runtime.h>
#include <hip/hip_bf16.h>

// ModConv2d: per-sample modulated 3x3 conv (N=8, C=64->64, 256x256) + MLPs.
// Kernel 1: MLPs -> w_bf[n][kidx][cb][cout][8ci] (bf16, A-frag 16B units) + bias.
// Kernel 2: implicit-GEMM conv, builtin mfma_f32_32x32x16_bf16, 8-ci chunks,
//   kidx-pair K=16 steps (5/chunk, pad pair s=4 reads zero A-slot).
//   Block: 512 thr (8 waves), 2 output rows x 256 cols x 64 couts; grid 1024.
//   Wave (wr, wq): row, 64-col quarter; acc[2][2] = 64 AGPR.
//   2 waves/SIMD with 256-reg budget -> compiler has headroom for frag
//   prefetch + DEPTH-2 staging: at chunk c, ISSUE loads for c+2 and WRITE
//   data for c+1 (loaded a full chunk earlier -> vmcnt stall fully covered).
//   Weights staged once (73.7 KB); x [4 rows][258][16B] dbuf 33 KB; 106.8 KB.
//   Raw s_barrier + lgkmcnt(0) only (global loads in flight across barriers).

typedef short bf16x8 __attribute__((ext_vector_type(8)));
typedef float f32x16 __attribute__((ext_vector_type(16)));

#define NB 8
#define CIN 64
#define COUT 64
#define HH 256
#define WW 256
#define HWP (HH * WW)
#define AUXD 128
#define HIDD 256

#define XRW8 (258 * 16)          // 4128 B: one staged row-plane (8 ci)
#define XBUF8 (4 * XRW8)         // 16512 B per buffer
#define WOFF (2 * XBUF8)         // 33024
#define WUNITS (9 * 8 * 64)      // 4608 16B units
#define SMEMB (WOFF + (WUNITS + 1) * 16)  // 106768

__device__ __forceinline__ unsigned short f2bf(float f) {
    unsigned u = __builtin_bit_cast(unsigned, f);
    u += 0x7FFFu + ((u >> 16) & 1u);   // RNE
    return (unsigned short)(u >> 16);
}

__device__ __forceinline__ unsigned pk2(float a, float b, float vm) {
    return (unsigned)f2bf(a * vm) | ((unsigned)f2bf(b * vm) << 16);
}

// ---------------- Kernel 1: MLPs ----------------
__global__ __launch_bounds__(256) void mlp_kernel(
    const float* __restrict__ y, const float* __restrict__ weight,
    const float* __restrict__ fc_w1, const float* __restrict__ fc_b1,
    const float* __restrict__ fc_prelu,
    const float* __restrict__ fc_w2, const float* __restrict__ fc_b2,
    const float* __restrict__ bias_w1, const float* __restrict__ bias_b1,
    const float* __restrict__ bias_prelu,
    const float* __restrict__ bias_w2, const float* __restrict__ bias_b2,
    unsigned short* __restrict__ w_bf, float* __restrict__ bvec)
{
    const int n = blockIdx.y;
    const int c = blockIdx.x;
    const int tid = threadIdx.x;
    __shared__ float ylds[AUXD];
    __shared__ float hl[HIDD];
    if (tid < AUXD) ylds[tid] = y[n * AUXD + tid];
    __syncthreads();

    if (c < 16) {
        float s = fc_b1[tid];
        const float* wrow = fc_w1 + tid * AUXD;
        #pragma unroll 4
        for (int a = 0; a < AUXD; ++a) s += ylds[a] * wrow[a];
        float ap = fc_prelu[0];
        hl[tid] = s >= 0.f ? s : ap * s;
        __syncthreads();

        int o = c * 256 + tid;           // o = cout*64 + ci
        float t = fc_b2[o];
        const float* w2row = fc_w2 + o * HIDD;
        #pragma unroll 4
        for (int h = 0; h < HIDD; ++h) t += hl[h] * w2row[h];
        float mod = 1.f / (1.f + expf(-t));
        int cout = o >> 6, ci = o & 63;
        int cb = ci >> 3, cl = ci & 7;
        #pragma unroll
        for (int k = 0; k < 9; ++k) {
            float wv = weight[o * 9 + k];
            // 16B unit = ((n*9+k)*8 + cb)*64 + cout; halfword cl
            w_bf[((((n * 9 + k) * 8 + cb) * 64 + cout) << 3) + cl] = f2bf(mod * wv);
        }
    } else {
        float s = bias_b1[tid];
        const float* wrow = bias_w1 + tid * AUXD;
        #pragma unroll 4
        for (int a = 0; a < AUXD; ++a) s += ylds[a] * wrow[a];
        float ap = bias_prelu[0];
        hl[tid] = s >= 0.f ? s : ap * s;
        __syncthreads();
        if (tid < COUT) {
            float t = bias_b2[tid];
            const float* w2row = bias_w2 + tid * HIDD;
            #pragma unroll 4
            for (int h = 0; h < HIDD; ++h) t += hl[h] * w2row[h];
            bvec[n * COUT + tid] = t;
        }
    }
}

// ---------------- Kernel 2: conv ----------------
#define XISSUE0(g, cc) { _Pragma("unroll") \
    for (int i = 0; i < 8; ++i) stg[g][0][i] = xp0[(size_t)((cc) * 8 + i) * HWP]; }
#define XISSUE1(g, cc) { _Pragma("unroll") \
    for (int i = 0; i < 8; ++i) stg[g][1][i] = xp1[(size_t)((cc) * 8 + i) * HWP]; }

#define XWRITE0(g, buf) { uint4 v_; const float* s_ = stg[g][0]; \
    v_.x = pk2(s_[0], s_[1], vm0); v_.y = pk2(s_[2], s_[3], vm0); \
    v_.z = pk2(s_[4], s_[5], vm0); v_.w = pk2(s_[6], s_[7], vm0); \
    *(uint4*)((buf) + r0 * XRW8 + (w + 1) * 16) = v_; }
#define XWRITE1(g, buf) { uint4 v_; const float* s_ = stg[g][1]; \
    v_.x = pk2(s_[0], s_[1], vm1); v_.y = pk2(s_[2], s_[3], vm1); \
    v_.z = pk2(s_[4], s_[5], vm1); v_.w = pk2(s_[6], s_[7], vm1); \
    *(uint4*)((buf) + r1 * XRW8 + (w + 1) * 16) = v_; }

__global__ __launch_bounds__(512, 2) void conv_kernel(
    const float* __restrict__ x, const unsigned short* __restrict__ w_bf,
    const float* __restrict__ bvec, float* __restrict__ out)
{
    __shared__ __align__(16) unsigned char smem[SMEMB];

    const int bid = blockIdx.x;
    const int n = bid & 7;              // sample -> XCD (x/weights L2 locality)
    const int h0 = (bid >> 3) * 2;      // first output row

    const int tid = threadIdx.x;
    const int lane = tid & 63;
    const int wave = tid >> 6;
    const int wr = wave >> 2;           // output row 0..1
    const int wq = wave & 3;            // 64-col quarter
    const int l5 = lane >> 5;           // K half (selects kidx of the pair)
    const int l31 = lane & 31;

    // staging: each thread owns 2 entries: (row r0, col w) and (row r1, col w)
    const int w = tid & 255;
    const int r0 = tid >> 8;            // 0..1
    const int r1 = r0 + 2;              // 2..3

    int hin0 = h0 - 1 + r0;
    bool v0 = (hin0 >= 0) && (hin0 < HH);
    const float vm0 = v0 ? 1.f : 0.f;
    const float* xp0 = x + (size_t)n * CIN * HWP + (size_t)(v0 ? hin0 : 0) * WW + w;
    int hin1 = h0 - 1 + r1;
    bool v1 = (hin1 >= 0) && (hin1 < HH);
    const float vm1 = v1 ? 1.f : 0.f;
    const float* xp1 = x + (size_t)n * CIN * HWP + (size_t)(v1 ? hin1 : 0) * WW + w;

    // ---- prologue: stage ALL weights (once) ----
    {
        const uint4* wsrc = (const uint4*)w_bf + (size_t)n * WUNITS;
        #pragma unroll
        for (int it = 0; it < 9; ++it) {
            int u = it * 512 + tid;
            *(uint4*)(smem + WOFF + (u << 4)) = wsrc[u];
        }
    }
    // zero halo entries (w-index 0 and 257): 2 bufs x 4 rows x 2 sides = 16
    if (tid < 16) {
        int buf = tid >> 3, rr = (tid >> 1) & 3, side = tid & 1;
        uint4 z; z.x = z.y = z.z = z.w = 0u;
        *(uint4*)(smem + buf * XBUF8 + rr * XRW8 + (side ? 257 : 0) * 16) = z;
    }
    if (tid == 16) {  // zero A-pad unit
        uint4 z; z.x = z.y = z.z = z.w = 0u;
        *(uint4*)(smem + WOFF + (WUNITS << 4)) = z;
    }

    // depth-2 staging pipeline state: group g holds the chunk with parity g
    float stg[2][2][8];

    // prologue: chunk 0 -> buf0 (write immediately); chunk 1 loads in flight
    XISSUE0(0, 0); XISSUE1(0, 0);
    XWRITE0(0, smem); XWRITE1(0, smem);
    XISSUE0(1, 1); XISSUE1(1, 1);

    // acc init = per-cout bias (D row = (reg&3) + 8*(reg>>2) + 4*l5)
    f32x16 acc[2][2];
    #pragma unroll
    for (int m = 0; m < 2; ++m) {
        #pragma unroll
        for (int reg = 0; reg < 16; ++reg)
            acc[m][0][reg] = bvec[n * COUT + m * 32 + (reg & 3) + 8 * (reg >> 2) + 4 * l5];
        acc[m][1] = acc[m][0];
    }

    asm volatile("s_waitcnt lgkmcnt(0)" ::: "memory");
    __builtin_amdgcn_s_barrier();

    #pragma unroll
    for (int c = 0; c < 8; ++c) {
        const int p = c & 1;
        const unsigned char* rbuf = smem + p * XBUF8;
        unsigned char* nx = smem + (p ^ 1) * XBUF8;

        #pragma unroll
        for (int s = 0; s < 5; ++s) {
            const int ka = 2 * s;                     // 0,2,4,6,8
            const int kb = (s == 4) ? 8 : 2 * s + 1;  // pad pair at s=4
            const bool solo = (s == 4);
            const int khA = ka / 3, kwA = ka % 3;
            const int khB = kb / 3, kwB = kb % 3;
            const int kh = l5 ? khB : khA;
            const int kw = l5 ? kwB : kwA;

            // A-frags: lane holds A[cout = m*32+l31][k = 8*l5 + j]
            int au = (solo && l5) ? WUNITS : ((l5 ? kb : ka) * 8 + c) * 64 + l31;
            int am = (solo && l5) ? 0 : 32;
            bf16x8 aA = *(const bf16x8*)(smem + WOFF + (au << 4));
            bf16x8 aB = *(const bf16x8*)(smem + WOFF + ((au + am) << 4));

            // B-frags: lane holds B[k][col = l31] = x[wr+kh][col+kw]
            const unsigned char* bb = rbuf + (wr + kh) * XRW8;
            bf16x8 b0 = *(const bf16x8*)(bb + ((wq * 64 + l31 + kw) << 4));
            bf16x8 b1 = *(const bf16x8*)(bb + ((wq * 64 + 32 + l31 + kw) << 4));

            // depth-2 staging: issue c+2 early, write c+1 late
            if (s == 0 && c < 6) { XISSUE0(p, c + 2); }
            if (s == 1 && c < 6) { XISSUE1(p, c + 2); }
            if (s == 3 && c < 7) { XWRITE0(p ^ 1, nx); }
            if (s == 4 && c < 7) { XWRITE1(p ^ 1, nx); }

            __builtin_amdgcn_s_setprio(1);
            acc[0][0] = __builtin_amdgcn_mfma_f32_32x32x16_bf16(aA, b0, acc[0][0], 0, 0, 0);
            acc[0][1] = __builtin_amdgcn_mfma_f32_32x32x16_bf16(aA, b1, acc[0][1], 0, 0, 0);
            acc[1][0] = __builtin_amdgcn_mfma_f32_32x32x16_bf16(aB, b0, acc[1][0], 0, 0, 0);
            acc[1][1] = __builtin_amdgcn_mfma_f32_32x32x16_bf16(aB, b1, acc[1][1], 0, 0, 0);
            __builtin_amdgcn_s_setprio(0);
        }

        // end-of-chunk: drain LDS ops only; global loads stay outstanding
        asm volatile("s_waitcnt lgkmcnt(0)" ::: "memory");
        __builtin_amdgcn_s_barrier();
    }

    // epilogue: D col = l31, row = (reg&3) + 8*(reg>>2) + 4*l5
    const int hout = h0 + wr;
    float* ob = out + ((size_t)n * COUT * HH + hout) * WW;
    #pragma unroll
    for (int m = 0; m < 2; ++m) {
        #pragma unroll
        for (int j = 0; j < 2; ++j) {
            int colb = wq * 64 + j * 32 + l31;
            #pragma unroll
            for (int reg = 0; reg < 16; ++reg) {
                int cout = m * 32 + (reg & 3) + 8 * (reg >> 2) + 4 * l5;
                ob[(size_t)cout * HWP + colb] = acc[m][j][reg];
            }
        }
    }
}

extern "C" void kernel_launch(void* const* d_in, const int* in_sizes, int n_in,
                              void* d_out, int out_size, void* d_ws, size_t ws_size,
                              hipStream_t stream) {
    const float* x          = (const float*)d_in[0];
    const float* y          = (const float*)d_in[1];
    const float* weight     = (const float*)d_in[2];
    const float* fc_w1      = (const float*)d_in[3];
    const float* fc_b1      = (const float*)d_in[4];
    const float* fc_prelu   = (const float*)d_in[5];
    const float* fc_w2      = (const float*)d_in[6];
    const float* fc_b2      = (const float*)d_in[7];
    const float* bias_w1    = (const float*)d_in[8];
    const float* bias_b1    = (const float*)d_in[9];
    const float* bias_prelu = (const float*)d_in[10];
    const float* bias_w2    = (const float*)d_in[11];
    const float* bias_b2    = (const float*)d_in[12];
    float* out = (float*)d_out;

    unsigned short* w_bf = (unsigned short*)d_ws;                       // 589824 B
    float* bvec = (float*)((char*)d_ws + (size_t)NB * 9 * 64 * 64 * 2); // 2048 B

    hipLaunchKernelGGL(mlp_kernel, dim3(17, 8), dim3(256), 0, stream,
                       y, weight, fc_w1, fc_b1, fc_prelu, fc_w2, fc_b2,
                       bias_w1, bias_b1, bias_prelu, bias_w2, bias_b2, w_bf, bvec);
    hipLaunchKernelGGL(conv_kernel, dim3(1024), dim3(512), 0, stream,
                       x, w_bf, bvec, out);
}

// Round 11
// 89.271 us; speedup vs baseline: 1.0281x; 1.0281x over previous
//
#include <hip/hip_runtime.h>
#include <hip/hip_bf16.h>

// ModConv2d: per-sample modulated 3x3 conv (N=8, C=64->64, 256x256) + MLPs.
// Kernel 1: MLPs -> w_bf[n][kidx][cb][cout][8ci] (bf16, A-frag 16B units) + bias.
// Kernel 2: implicit-GEMM conv, builtin mfma_f32_32x32x16_bf16, 8-ci chunks,
//   kidx-pair K=16 steps (5/chunk, pad pair s=4 reads zero A-slot).
//   Block: 512 thr (8 waves), 2 output rows x 256 cols x 64 couts; grid 1024.
//   Wave (wr, wq): row, 64-col quarter; acc[2][2] = 64 AGPR.
//   R11 staging revamp: each thread owns (row tid>>7, cols 2cp..2cp+1);
//   per chunk: 8 x dwordx2 loads (512B/wave contiguous) + 8 v_cvt_pk_bf16_f32
//   (inline asm) + 2 ds_write_b128. Replaces 16 scalar dword loads + ~100
//   VALU pack ops. Edge rows: cndmask zero-select (loads stay issued early).
//   Depth-2 staging (issue c+2 at s0, write c+1 at s3), raw s_barrier +
//   lgkmcnt(0) only, setprio around MFMA cluster. LDS 106.8 KB, (512,2).

typedef short bf16x8 __attribute__((ext_vector_type(8)));
typedef float f32x16 __attribute__((ext_vector_type(16)));

#define NB 8
#define CIN 64
#define COUT 64
#define HH 256
#define WW 256
#define HWP (HH * WW)
#define AUXD 128
#define HIDD 256

#define XRW8 (258 * 16)          // 4128 B: one staged row-plane (8 ci)
#define XBUF8 (4 * XRW8)         // 16512 B per buffer
#define WOFF (2 * XBUF8)         // 33024
#define WUNITS (9 * 8 * 64)      // 4608 16B units
#define SMEMB (WOFF + (WUNITS + 1) * 16)  // 106768

__device__ __forceinline__ unsigned short f2bf(float f) {
    unsigned u = __builtin_bit_cast(unsigned, f);
    u += 0x7FFFu + ((u >> 16) & 1u);   // RNE
    return (unsigned short)(u >> 16);
}

__device__ __forceinline__ unsigned cvtpk(float a, float b) {
    unsigned r;  // r[15:0] = bf16(a), r[31:16] = bf16(b)
    asm volatile("v_cvt_pk_bf16_f32 %0, %1, %2" : "=v"(r) : "v"(a), "v"(b));
    return r;
}

// ---------------- Kernel 1: MLPs ----------------
__global__ __launch_bounds__(256) void mlp_kernel(
    const float* __restrict__ y, const float* __restrict__ weight,
    const float* __restrict__ fc_w1, const float* __restrict__ fc_b1,
    const float* __restrict__ fc_prelu,
    const float* __restrict__ fc_w2, const float* __restrict__ fc_b2,
    const float* __restrict__ bias_w1, const float* __restrict__ bias_b1,
    const float* __restrict__ bias_prelu,
    const float* __restrict__ bias_w2, const float* __restrict__ bias_b2,
    unsigned short* __restrict__ w_bf, float* __restrict__ bvec)
{
    const int n = blockIdx.y;
    const int c = blockIdx.x;
    const int tid = threadIdx.x;
    __shared__ float ylds[AUXD];
    __shared__ float hl[HIDD];
    if (tid < AUXD) ylds[tid] = y[n * AUXD + tid];
    __syncthreads();

    if (c < 16) {
        float s = fc_b1[tid];
        const float* wrow = fc_w1 + tid * AUXD;
        #pragma unroll 4
        for (int a = 0; a < AUXD; ++a) s += ylds[a] * wrow[a];
        float ap = fc_prelu[0];
        hl[tid] = s >= 0.f ? s : ap * s;
        __syncthreads();

        int o = c * 256 + tid;           // o = cout*64 + ci
        float t = fc_b2[o];
        const float* w2row = fc_w2 + o * HIDD;
        #pragma unroll 4
        for (int h = 0; h < HIDD; ++h) t += hl[h] * w2row[h];
        float mod = 1.f / (1.f + expf(-t));
        int cout = o >> 6, ci = o & 63;
        int cb = ci >> 3, cl = ci & 7;
        #pragma unroll
        for (int k = 0; k < 9; ++k) {
            float wv = weight[o * 9 + k];
            // 16B unit = ((n*9+k)*8 + cb)*64 + cout; halfword cl
            w_bf[((((n * 9 + k) * 8 + cb) * 64 + cout) << 3) + cl] = f2bf(mod * wv);
        }
    } else {
        float s = bias_b1[tid];
        const float* wrow = bias_w1 + tid * AUXD;
        #pragma unroll 4
        for (int a = 0; a < AUXD; ++a) s += ylds[a] * wrow[a];
        float ap = bias_prelu[0];
        hl[tid] = s >= 0.f ? s : ap * s;
        __syncthreads();
        if (tid < COUT) {
            float t = bias_b2[tid];
            const float* w2row = bias_w2 + tid * HIDD;
            #pragma unroll 4
            for (int h = 0; h < HIDD; ++h) t += hl[h] * w2row[h];
            bvec[n * COUT + tid] = t;
        }
    }
}

// ---------------- Kernel 2: conv ----------------
// staging: thread owns (row srow, cols 2cp, 2cp+1); 8 ci-planes per chunk.
#define XISSUE(g, cc) { _Pragma("unroll") \
    for (int i = 0; i < 8; ++i) \
        stg[g][i] = *(const float2*)(xps + (size_t)((cc) * 8 + i) * HWP); }

#define XWRITE(g, buf) { uint4 a_, b_; \
    a_.x = cvtpk(stg[g][0].x, stg[g][1].x); a_.y = cvtpk(stg[g][2].x, stg[g][3].x); \
    a_.z = cvtpk(stg[g][4].x, stg[g][5].x); a_.w = cvtpk(stg[g][6].x, stg[g][7].x); \
    b_.x = cvtpk(stg[g][0].y, stg[g][1].y); b_.y = cvtpk(stg[g][2].y, stg[g][3].y); \
    b_.z = cvtpk(stg[g][4].y, stg[g][5].y); b_.w = cvtpk(stg[g][6].y, stg[g][7].y); \
    if (!valid) { a_.x = a_.y = a_.z = a_.w = 0u; b_.x = b_.y = b_.z = b_.w = 0u; } \
    unsigned char* d_ = (buf) + srow * XRW8 + (w0 + 1) * 16; \
    *(uint4*)d_ = a_; *(uint4*)(d_ + 16) = b_; }

__global__ __launch_bounds__(512, 2) void conv_kernel(
    const float* __restrict__ x, const unsigned short* __restrict__ w_bf,
    const float* __restrict__ bvec, float* __restrict__ out)
{
    __shared__ __align__(16) unsigned char smem[SMEMB];

    const int bid = blockIdx.x;
    const int n = bid & 7;              // sample -> XCD (x/weights L2 locality)
    const int h0 = (bid >> 3) * 2;      // first output row

    const int tid = threadIdx.x;
    const int lane = tid & 63;
    const int wave = tid >> 6;
    const int wr = wave >> 2;           // output row 0..1
    const int wq = wave & 3;            // 64-col quarter
    const int l5 = lane >> 5;           // K half (selects kidx of the pair)
    const int l31 = lane & 31;

    // staging ownership: row srow (0..3), columns w0 = 2*cp, w0+1
    const int cp = tid & 127;
    const int srow = tid >> 7;          // 0..3
    const int w0 = cp * 2;

    const int hin = h0 - 1 + srow;
    const bool valid = (hin >= 0) && (hin < HH);
    const float* xps = x + (size_t)n * CIN * HWP + (size_t)(valid ? hin : 0) * WW + w0;

    // ---- prologue: stage ALL weights (once) ----
    {
        const uint4* wsrc = (const uint4*)w_bf + (size_t)n * WUNITS;
        #pragma unroll
        for (int it = 0; it < 9; ++it) {
            int u = it * 512 + tid;
            *(uint4*)(smem + WOFF + (u << 4)) = wsrc[u];
        }
    }
    // zero halo entries (w-index 0 and 257): 2 bufs x 4 rows x 2 sides = 16
    if (tid < 16) {
        int buf = tid >> 3, rr = (tid >> 1) & 3, side = tid & 1;
        uint4 z; z.x = z.y = z.z = z.w = 0u;
        *(uint4*)(smem + buf * XBUF8 + rr * XRW8 + (side ? 257 : 0) * 16) = z;
    }
    if (tid == 16) {  // zero A-pad unit
        uint4 z; z.x = z.y = z.z = z.w = 0u;
        *(uint4*)(smem + WOFF + (WUNITS << 4)) = z;
    }

    // depth-2 staging pipeline: group g holds the chunk with parity g
    float2 stg[2][8];

    XISSUE(0, 0);
    XWRITE(0, smem);     // chunk 0 -> buf0
    XISSUE(1, 1);        // chunk 1 in flight

    // acc init = per-cout bias (D row = (reg&3) + 8*(reg>>2) + 4*l5)
    f32x16 acc[2][2];
    #pragma unroll
    for (int m = 0; m < 2; ++m) {
        #pragma unroll
        for (int reg = 0; reg < 16; ++reg)
            acc[m][0][reg] = bvec[n * COUT + m * 32 + (reg & 3) + 8 * (reg >> 2) + 4 * l5];
        acc[m][1] = acc[m][0];
    }

    asm volatile("s_waitcnt lgkmcnt(0)" ::: "memory");
    __builtin_amdgcn_s_barrier();

    #pragma unroll
    for (int c = 0; c < 8; ++c) {
        const int p = c & 1;
        const unsigned char* rbuf = smem + p * XBUF8;
        unsigned char* nx = smem + (p ^ 1) * XBUF8;

        #pragma unroll
        for (int s = 0; s < 5; ++s) {
            const int ka = 2 * s;                     // 0,2,4,6,8
            const int kb = (s == 4) ? 8 : 2 * s + 1;  // pad pair at s=4
            const bool solo = (s == 4);
            const int khA = ka / 3, kwA = ka % 3;
            const int khB = kb / 3, kwB = kb % 3;
            const int kh = l5 ? khB : khA;
            const int kw = l5 ? kwB : kwA;

            // A-frags: lane holds A[cout = m*32+l31][k = 8*l5 + j]
            int au = (solo && l5) ? WUNITS : ((l5 ? kb : ka) * 8 + c) * 64 + l31;
            int am = (solo && l5) ? 0 : 32;
            bf16x8 aA = *(const bf16x8*)(smem + WOFF + (au << 4));
            bf16x8 aB = *(const bf16x8*)(smem + WOFF + ((au + am) << 4));

            // B-frags: lane holds B[k][col = l31] = x[wr+kh][col+kw]
            const unsigned char* bb = rbuf + (wr + kh) * XRW8;
            bf16x8 b0 = *(const bf16x8*)(bb + ((wq * 64 + l31 + kw) << 4));
            bf16x8 b1 = *(const bf16x8*)(bb + ((wq * 64 + 32 + l31 + kw) << 4));

            // depth-2 staging: issue c+2 early, write c+1 late
            if (s == 0 && c < 6) { XISSUE(p, c + 2); }
            if (s == 3 && c < 7) { XWRITE(p ^ 1, nx); }

            __builtin_amdgcn_s_setprio(1);
            acc[0][0] = __builtin_amdgcn_mfma_f32_32x32x16_bf16(aA, b0, acc[0][0], 0, 0, 0);
            acc[0][1] = __builtin_amdgcn_mfma_f32_32x32x16_bf16(aA, b1, acc[0][1], 0, 0, 0);
            acc[1][0] = __builtin_amdgcn_mfma_f32_32x32x16_bf16(aB, b0, acc[1][0], 0, 0, 0);
            acc[1][1] = __builtin_amdgcn_mfma_f32_32x32x16_bf16(aB, b1, acc[1][1], 0, 0, 0);
            __builtin_amdgcn_s_setprio(0);
        }

        // end-of-chunk: drain LDS ops only; global loads stay outstanding
        asm volatile("s_waitcnt lgkmcnt(0)" ::: "memory");
        __builtin_amdgcn_s_barrier();
    }

    // epilogue: D col = l31, row = (reg&3) + 8*(reg>>2) + 4*l5
    const int hout = h0 + wr;
    float* ob = out + ((size_t)n * COUT * HH + hout) * WW;
    #pragma unroll
    for (int m = 0; m < 2; ++m) {
        #pragma unroll
        for (int j = 0; j < 2; ++j) {
            int colb = wq * 64 + j * 32 + l31;
            #pragma unroll
            for (int reg = 0; reg < 16; ++reg) {
                int cout = m * 32 + (reg & 3) + 8 * (reg >> 2) + 4 * l5;
                ob[(size_t)cout * HWP + colb] = acc[m][j][reg];
            }
        }
    }
}

extern "C" void kernel_launch(void* const* d_in, const int* in_sizes, int n_in,
                              void* d_out, int out_size, void* d_ws, size_t ws_size,
                              hipStream_t stream) {
    const float* x          = (const float*)d_in[0];
    const float* y          = (const float*)d_in[1];
    const float* weight     = (const float*)d_in[2];
    const float* fc_w1      = (const float*)d_in[3];
    const float* fc_b1      = (const float*)d_in[4];
    const float* fc_prelu   = (const float*)d_in[5];
    const float* fc_w2      = (const float*)d_in[6];
    const float* fc_b2      = (const float*)d_in[7];
    const float* bias_w1    = (const float*)d_in[8];
    const float* bias_b1    = (const float*)d_in[9];
    const float* bias_prelu = (const float*)d_in[10];
    const float* bias_w2    = (const float*)d_in[11];
    const float* bias_b2    = (const float*)d_in[12];
    float* out = (float*)d_out;

    unsigned short* w_bf = (unsigned short*)d_ws;                       // 589824 B
    float* bvec = (float*)((char*)d_ws + (size_t)NB * 9 * 64 * 64 * 2); // 2048 B

    hipLaunchKernelGGL(mlp_kernel, dim3(17, 8), dim3(256), 0, stream,
                       y, weight, fc_w1, fc_b1, fc_prelu, fc_w2, fc_b2,
                       bias_w1, bias_b1, bias_prelu, bias_w2, bias_b2, w_bf, bvec);
    hipLaunchKernelGGL(conv_kernel, dim3(1024), dim3(512), 0, stream,
                       x, w_bf, bvec, out);
}

// Round 12
// 88.934 us; speedup vs baseline: 1.0320x; 1.0038x over previous
//
#include <hip/hip_runtime.h>
#include <hip/hip_bf16.h>

// ModConv2d: per-sample modulated 3x3 conv (N=8, C=64->64, 256x256) + MLPs.
// Kernel 1: MLPs -> w_bf[n][kidx][cb][cout][8ci] (bf16, A-frag 16B units) + bias.
// Kernel 2: implicit-GEMM conv, builtin mfma_f32_32x32x16_bf16, 8-ci chunks,
//   kidx-pair K=16 steps (5/chunk, pad pair s=4 reads zero A-slot).
//   R12 "persistent band": grid 256 (1 block/CU, single generation).
//   Block: 512 thr (8 waves) owns an 8-row band (4 row-pairs) of one sample.
//   Per pair: 8 chunks x 5 steps (acc[2][2] = 64 AGPR/wave), then 64
//   fire-and-forget stores + acc reinit from preloaded bias — store drain
//   overlaps next pair's compute (kills the per-generation burst serialization
//   that pinned R5..R11 at ~82us). Weights staged ONCE per block (73.7 KB).
//   x LDS [4 rows][258][16B] dbuf (33 KB); rolling 3-row-ptr window between
//   pairs (next pair rowA = cur rowB). Staging: thread owns 1 col x 2 rows,
//   16 scalar dword loads + cvt_pk_bf16 + 2 stride-16B ds_write_b128
//   (conflict-free, R10-proven). Raw s_barrier + lgkmcnt(0) only; depth-2
//   ISSUE/WRITE; setprio around MFMA cluster. LDS 106.8 KB, (512,2).

typedef short bf16x8 __attribute__((ext_vector_type(8)));
typedef float f32x16 __attribute__((ext_vector_type(16)));

#define NB 8
#define CIN 64
#define COUT 64
#define HH 256
#define WW 256
#define HWP (HH * WW)
#define AUXD 128
#define HIDD 256

#define XRW8 (258 * 16)          // 4128 B: one staged row-plane (8 ci)
#define XBUF8 (4 * XRW8)         // 16512 B per buffer
#define WOFF (2 * XBUF8)         // 33024
#define WUNITS (9 * 8 * 64)      // 4608 16B units
#define SMEMB (WOFF + (WUNITS + 1) * 16)  // 106768

__device__ __forceinline__ unsigned short f2bf(float f) {
    unsigned u = __builtin_bit_cast(unsigned, f);
    u += 0x7FFFu + ((u >> 16) & 1u);   // RNE
    return (unsigned short)(u >> 16);
}

__device__ __forceinline__ unsigned cvtpk(float a, float b) {
    unsigned r;  // r[15:0] = bf16(a), r[31:16] = bf16(b)
    asm volatile("v_cvt_pk_bf16_f32 %0, %1, %2" : "=v"(r) : "v"(a), "v"(b));
    return r;
}

// ---------------- Kernel 1: MLPs ----------------
__global__ __launch_bounds__(256) void mlp_kernel(
    const float* __restrict__ y, const float* __restrict__ weight,
    const float* __restrict__ fc_w1, const float* __restrict__ fc_b1,
    const float* __restrict__ fc_prelu,
    const float* __restrict__ fc_w2, const float* __restrict__ fc_b2,
    const float* __restrict__ bias_w1, const float* __restrict__ bias_b1,
    const float* __restrict__ bias_prelu,
    const float* __restrict__ bias_w2, const float* __restrict__ bias_b2,
    unsigned short* __restrict__ w_bf, float* __restrict__ bvec)
{
    const int n = blockIdx.y;
    const int c = blockIdx.x;
    const int tid = threadIdx.x;
    __shared__ float ylds[AUXD];
    __shared__ float hl[HIDD];
    if (tid < AUXD) ylds[tid] = y[n * AUXD + tid];
    __syncthreads();

    if (c < 16) {
        float s = fc_b1[tid];
        const float* wrow = fc_w1 + tid * AUXD;
        #pragma unroll 4
        for (int a = 0; a < AUXD; ++a) s += ylds[a] * wrow[a];
        float ap = fc_prelu[0];
        hl[tid] = s >= 0.f ? s : ap * s;
        __syncthreads();

        int o = c * 256 + tid;           // o = cout*64 + ci
        float t = fc_b2[o];
        const float* w2row = fc_w2 + o * HIDD;
        #pragma unroll 4
        for (int h = 0; h < HIDD; ++h) t += hl[h] * w2row[h];
        float mod = 1.f / (1.f + expf(-t));
        int cout = o >> 6, ci = o & 63;
        int cb = ci >> 3, cl = ci & 7;
        #pragma unroll
        for (int k = 0; k < 9; ++k) {
            float wv = weight[o * 9 + k];
            // 16B unit = ((n*9+k)*8 + cb)*64 + cout; halfword cl
            w_bf[((((n * 9 + k) * 8 + cb) * 64 + cout) << 3) + cl] = f2bf(mod * wv);
        }
    } else {
        float s = bias_b1[tid];
        const float* wrow = bias_w1 + tid * AUXD;
        #pragma unroll 4
        for (int a = 0; a < AUXD; ++a) s += ylds[a] * wrow[a];
        float ap = bias_prelu[0];
        hl[tid] = s >= 0.f ? s : ap * s;
        __syncthreads();
        if (tid < COUT) {
            float t = bias_b2[tid];
            const float* w2row = bias_w2 + tid * HIDD;
            #pragma unroll 4
            for (int h = 0; h < HIDD; ++h) t += hl[h] * w2row[h];
            bvec[n * COUT + tid] = t;
        }
    }
}

// ---------------- Kernel 2: conv ----------------
// staging: thread owns (row r0, col w) and (row r0+2, col w); 8 ci/chunk each.
#define XISSUE(g, pA, pB, cc) { _Pragma("unroll") \
    for (int i = 0; i < 8; ++i) { \
        stg[g][i]     = (pA)[(size_t)((cc) * 8 + i) * HWP]; \
        stg[g][8 + i] = (pB)[(size_t)((cc) * 8 + i) * HWP]; } }

#define XWRITE(g, bA, bB, buf) { \
    uint4 u0_, u1_; \
    u0_.x = cvtpk(stg[g][0], stg[g][1]);   u0_.y = cvtpk(stg[g][2], stg[g][3]); \
    u0_.z = cvtpk(stg[g][4], stg[g][5]);   u0_.w = cvtpk(stg[g][6], stg[g][7]); \
    u1_.x = cvtpk(stg[g][8], stg[g][9]);   u1_.y = cvtpk(stg[g][10], stg[g][11]); \
    u1_.z = cvtpk(stg[g][12], stg[g][13]); u1_.w = cvtpk(stg[g][14], stg[g][15]); \
    if (!(bA)) { u0_.x = u0_.y = u0_.z = u0_.w = 0u; } \
    if (!(bB)) { u1_.x = u1_.y = u1_.z = u1_.w = 0u; } \
    *(uint4*)((buf) + r0 * XRW8 + (w + 1) * 16) = u0_; \
    *(uint4*)((buf) + (r0 + 2) * XRW8 + (w + 1) * 16) = u1_; }

__global__ __launch_bounds__(512, 2) void conv_kernel(
    const float* __restrict__ x, const unsigned short* __restrict__ w_bf,
    const float* __restrict__ bvec, float* __restrict__ out)
{
    __shared__ __align__(16) unsigned char smem[SMEMB];

    const int bid = blockIdx.x;
    const int n = bid & 7;              // sample -> XCD (x/weights L2 locality)
    const int h0 = (bid >> 3) * 8;      // 8-row band (4 row-pairs)

    const int tid = threadIdx.x;
    const int lane = tid & 63;
    const int wave = tid >> 6;
    const int wr = wave >> 2;           // output row within pair 0..1
    const int wq = wave & 3;            // 64-col quarter
    const int l5 = lane >> 5;           // K half (selects kidx of the pair)
    const int l31 = lane & 31;

    const int w = tid & 255;            // staging col
    const int r0 = tid >> 8;            // 0..1; thread stages rows r0, r0+2

    const float* xb = x + (size_t)n * CIN * HWP + w;

    // ---- prologue: stage ALL weights (once per block) ----
    {
        const uint4* wsrc = (const uint4*)w_bf + (size_t)n * WUNITS;
        #pragma unroll
        for (int it = 0; it < 9; ++it) {
            int u = it * 512 + tid;
            *(uint4*)(smem + WOFF + (u << 4)) = wsrc[u];
        }
    }
    // zero halo entries (w-index 0 and 257): 2 bufs x 4 rows x 2 sides = 16
    if (tid < 16) {
        int buf = tid >> 3, rr = (tid >> 1) & 3, side = tid & 1;
        uint4 z; z.x = z.y = z.z = z.w = 0u;
        *(uint4*)(smem + buf * XBUF8 + rr * XRW8 + (side ? 257 : 0) * 16) = z;
    }
    if (tid == 16) {  // zero A-pad unit
        uint4 z; z.x = z.y = z.z = z.w = 0u;
        *(uint4*)(smem + WOFF + (WUNITS << 4)) = z;
    }

    // bias preload (D row = (reg&3) + 8*(reg>>2) + 4*l5)
    f32x16 bia[2];
    #pragma unroll
    for (int m = 0; m < 2; ++m)
        #pragma unroll
        for (int reg = 0; reg < 16; ++reg)
            bia[m][reg] = bvec[n * COUT + m * 32 + (reg & 3) + 8 * (reg >> 2) + 4 * l5];

    // rolling row window for this thread: rows hA = base+r0, hB = base+r0+2,
    // base = h0 + 2*pair - 1. Next pair: rowA' = rowB, rowB' = rowB + 2.
    int hA = h0 - 1 + r0;
    bool vA = (hA >= 0);                        // hA < HH always at pair 0
    const float* xpA = xb + (size_t)(vA ? hA : 0) * WW;
    int hB = hA + 2;
    bool vB = true;                             // h0+1+r0 <= 255 always
    const float* xpB = xb + (size_t)hB * WW;

    // depth-2 staging state
    float stg[2][16];

    // prologue staging: pair0 chunk0 -> buf0; chunk1 loads in flight
    XISSUE(0, xpA, xpB, 0);
    XWRITE(0, vA, vB, smem);
    XISSUE(1, xpA, xpB, 1);

    f32x16 acc[2][2];
    acc[0][0] = bia[0]; acc[0][1] = bia[0];
    acc[1][0] = bia[1]; acc[1][1] = bia[1];

    asm volatile("s_waitcnt lgkmcnt(0)" ::: "memory");
    __builtin_amdgcn_s_barrier();

    for (int pair = 0; pair < 4; ++pair) {
        // next-pair new row (rowB + 2)
        const int hC = hB + 2;
        const bool vC = (hC < HH);
        const float* xpC = xb + (size_t)(vC ? hC : 0) * WW;
        const bool morep = (pair < 3);

        #pragma unroll
        for (int c = 0; c < 8; ++c) {
            const int p = c & 1;
            const unsigned char* rbuf = smem + p * XBUF8;
            unsigned char* nx = smem + (p ^ 1) * XBUF8;

            #pragma unroll
            for (int s = 0; s < 5; ++s) {
                const int ka = 2 * s;                     // 0,2,4,6,8
                const int kb = (s == 4) ? 8 : 2 * s + 1;  // pad pair at s=4
                const bool solo = (s == 4);
                const int khA_ = ka / 3, kwA_ = ka % 3;
                const int khB_ = kb / 3, kwB_ = kb % 3;
                const int kh = l5 ? khB_ : khA_;
                const int kw = l5 ? kwB_ : kwA_;

                // A-frags: lane holds A[cout = m*32+l31][k = 8*l5 + j]
                int au = (solo && l5) ? WUNITS : ((l5 ? kb : ka) * 8 + c) * 64 + l31;
                int am = (solo && l5) ? 0 : 32;
                bf16x8 aA = *(const bf16x8*)(smem + WOFF + (au << 4));
                bf16x8 aB = *(const bf16x8*)(smem + WOFF + ((au + am) << 4));

                // B-frags: lane holds B[k][col = l31] = x[wr+kh][col+kw]
                const unsigned char* bb = rbuf + (wr + kh) * XRW8;
                bf16x8 b0 = *(const bf16x8*)(bb + ((wq * 64 + l31 + kw) << 4));
                bf16x8 b1 = *(const bf16x8*)(bb + ((wq * 64 + 32 + l31 + kw) << 4));

                // depth-2 staging; pair boundary rolls the row window
                if (s == 0) {
                    if (c < 6)                 { XISSUE(p, xpA, xpB, c + 2); }
                    else if (c == 6 && morep)  { XISSUE(0, xpB, xpC, 0); }
                    else if (c == 7 && morep)  { XISSUE(1, xpB, xpC, 1); }
                }
                if (s == 3) {
                    if (c < 7)                 { XWRITE((c + 1) & 1, vA, vB, nx); }
                    else if (morep)            { XWRITE(0, vB, vC, nx); }
                }

                __builtin_amdgcn_s_setprio(1);
                acc[0][0] = __builtin_amdgcn_mfma_f32_32x32x16_bf16(aA, b0, acc[0][0], 0, 0, 0);
                acc[0][1] = __builtin_amdgcn_mfma_f32_32x32x16_bf16(aA, b1, acc[0][1], 0, 0, 0);
                acc[1][0] = __builtin_amdgcn_mfma_f32_32x32x16_bf16(aB, b0, acc[1][0], 0, 0, 0);
                acc[1][1] = __builtin_amdgcn_mfma_f32_32x32x16_bf16(aB, b1, acc[1][1], 0, 0, 0);
                __builtin_amdgcn_s_setprio(0);
            }

            // end-of-chunk: drain LDS ops only; global loads/stores stay out
            asm volatile("s_waitcnt lgkmcnt(0)" ::: "memory");
            __builtin_amdgcn_s_barrier();
        }

        // fire-and-forget stores for this pair (drain overlaps next pair)
        {
            const int hout = h0 + 2 * pair + wr;
            float* ob = out + ((size_t)n * COUT * HH + hout) * WW;
            #pragma unroll
            for (int m = 0; m < 2; ++m) {
                #pragma unroll
                for (int j = 0; j < 2; ++j) {
                    int colb = wq * 64 + j * 32 + l31;
                    #pragma unroll
                    for (int reg = 0; reg < 16; ++reg) {
                        int cout = m * 32 + (reg & 3) + 8 * (reg >> 2) + 4 * l5;
                        ob[(size_t)cout * HWP + colb] = acc[m][j][reg];
                    }
                }
            }
        }

        if (morep) {
            acc[0][0] = bia[0]; acc[0][1] = bia[0];
            acc[1][0] = bia[1]; acc[1][1] = bia[1];
            // roll the row window
            xpA = xpB; vA = vB;
            xpB = xpC; vB = vC;
            hB = hC;
        }
    }
}

extern "C" void kernel_launch(void* const* d_in, const int* in_sizes, int n_in,
                              void* d_out, int out_size, void* d_ws, size_t ws_size,
                              hipStream_t stream) {
    const float* x          = (const float*)d_in[0];
    const float* y          = (const float*)d_in[1];
    const float* weight     = (const float*)d_in[2];
    const float* fc_w1      = (const float*)d_in[3];
    const float* fc_b1      = (const float*)d_in[4];
    const float* fc_prelu   = (const float*)d_in[5];
    const float* fc_w2      = (const float*)d_in[6];
    const float* fc_b2      = (const float*)d_in[7];
    const float* bias_w1    = (const float*)d_in[8];
    const float* bias_b1    = (const float*)d_in[9];
    const float* bias_prelu = (const float*)d_in[10];
    const float* bias_w2    = (const float*)d_in[11];
    const float* bias_b2    = (const float*)d_in[12];
    float* out = (float*)d_out;

    unsigned short* w_bf = (unsigned short*)d_ws;                       // 589824 B
    float* bvec = (float*)((char*)d_ws + (size_t)NB * 9 * 64 * 64 * 2); // 2048 B

    hipLaunchKernelGGL(mlp_kernel, dim3(17, 8), dim3(256), 0, stream,
                       y, weight, fc_w1, fc_b1, fc_prelu, fc_w2, fc_b2,
                       bias_w1, bias_b1, bias_prelu, bias_w2, bias_b2, w_bf, bvec);
    hipLaunchKernelGGL(conv_kernel, dim3(256), dim3(512), 0, stream,
                       x, w_bf, bvec, out);
}